// Round 4
// baseline (392.964 us; speedup 1.0000x reference)
//
#include <hip/hip_runtime.h>
#include <hip/hip_bf16.h>
#include <hip/hip_fp16.h>
#include <type_traits>

constexpr int BB = 4;
constexpr int CC = 512;
constexpr int HH = 4096;
constexpr int IC = 256;

typedef _Float16 f16x8v __attribute__((ext_vector_type(8)));
typedef __bf16   bf16x8v __attribute__((ext_vector_type(8)));
typedef float    f32x4v __attribute__((ext_vector_type(4)));

__device__ __forceinline__ void gll16(const void* g, void* l) {
  __builtin_amdgcn_global_load_lds(
      (const __attribute__((address_space(1))) unsigned int*)g,
      (__attribute__((address_space(3))) unsigned int*)l, 16, 0, 0);
}

__device__ __forceinline__ f32x4v mfma16(f16x8v a, f16x8v b, f32x4v c) {
  return __builtin_amdgcn_mfma_f32_16x16x32_f16(a, b, c, 0, 0, 0);
}
__device__ __forceinline__ f32x4v mfma16(bf16x8v a, bf16x8v b, f32x4v c) {
  return __builtin_amdgcn_mfma_f32_16x16x32_bf16(a, b, c, 0, 0, 0);
}

__device__ __forceinline__ unsigned short hbits(float f) {
  __half h = __float2half(f);
  unsigned short b; __builtin_memcpy(&b, &h, 2); return b;
}
__device__ __forceinline__ unsigned short bbits(float f) {
  __hip_bfloat16 h = __float2bfloat16(f);
  unsigned short b; __builtin_memcpy(&b, &h, 2); return b;
}

// ---------------------------------------------------------------------------
// 128x128-tile B^T GEMM: D[m][n] = sum_k A[m,k]*B[n,k]; A,B k-contiguous.
// 256 thr = 4 waves (64x64 quadrants). C/D: col(n)=lane&15, row(m)=quad*4+reg
// -> reg spans 4 CONSECUTIVE m; output contiguous dim is always m, so stores
// are 8-16B packed at out[b*sOb + n*M + m0].
// MODE 0 (theta/phi dual, which=blockIdx.z>>2 selects A/bias/out): fp16, +bias[m]
// MODE 1 (g):      bf16, +bias[n]
// MODE 2 (scores): bf16 exp(v); Z[b,m] += sum over n (shfl+atomic)
// MODE 3 (final):  fp32, +bias[n] + xres
// ---------------------------------------------------------------------------
template <int MODE>
__launch_bounds__(256)
__global__ void mgemm128(const void* __restrict__ Aall, const void* __restrict__ Aall2,
                         const void* __restrict__ Ball,
                         void* __restrict__ outP, void* __restrict__ out2P,
                         const float* __restrict__ bias, const float* __restrict__ bias2,
                         const float* __restrict__ xres, float* __restrict__ Z,
                         int M, int N, int K,
                         size_t sAb, size_t sBb, size_t sOb) {
  using ET = typename std::conditional<MODE == 3, bf16x8v, f16x8v>::type;

  __shared__ __align__(16) unsigned short sA[128 * 32];
  __shared__ __align__(16) unsigned short sB[128 * 32];

  const int zz = blockIdx.z;
  int b, which;
  if constexpr (MODE == 0) { b = zz & (BB - 1); which = zz >> 2; }
  else { b = zz; which = 0; }

  const unsigned short* __restrict__ A =
      (const unsigned short*)((MODE == 0 && which) ? Aall2 : Aall) + (size_t)b * sAb;
  const unsigned short* __restrict__ Bm = (const unsigned short*)Ball + (size_t)b * sBb;
  const float* __restrict__ biasSel = (MODE == 0 && which) ? bias2 : bias;
  void* __restrict__ outSel = (MODE == 0 && which) ? out2P : outP;

  const int t = threadIdx.x;
  const int lane = t & 63;
  const int w = t >> 6;
  const int wm = (w >> 1) << 6;
  const int wn = (w & 1) << 6;
  const int mBase = blockIdx.y * 128;
  const int nBase = blockIdx.x * 128;

  const int fr = lane & 15;
  const int fo = (lane >> 4) << 3;

  f32x4v acc[4][4] = {};

  for (int k0 = 0; k0 < K; k0 += 32) {
#pragma unroll
    for (int p = 0; p < 2; ++p) {
      const int u = t + (p << 8);
      const int r = u >> 2;
      const int cs = (u & 3) << 3;
      gll16(A + (size_t)(mBase + r) * K + (k0 + cs), sA + u * 8);
      gll16(Bm + (size_t)(nBase + r) * K + (k0 + cs), sB + u * 8);
    }
    __syncthreads();
    ET af[4], bf[4];
#pragma unroll
    for (int i = 0; i < 4; ++i)
      af[i] = *(const ET*)(sA + ((wm + (i << 4) + fr) << 5) + fo);
#pragma unroll
    for (int j = 0; j < 4; ++j)
      bf[j] = *(const ET*)(sB + ((wn + (j << 4) + fr) << 5) + fo);
#pragma unroll
    for (int i = 0; i < 4; ++i)
#pragma unroll
      for (int j = 0; j < 4; ++j)
        acc[i][j] = mfma16(af[i], bf[j], acc[i][j]);
    __syncthreads();
  }

  const int quad = lane >> 4;
  const int col = lane & 15;

  if constexpr (MODE == 2) {
    unsigned short* __restrict__ outB = (unsigned short*)outP;
    float csum[4][4];
#pragma unroll
    for (int i = 0; i < 4; ++i)
#pragma unroll
      for (int rg = 0; rg < 4; ++rg) csum[i][rg] = 0.f;
#pragma unroll
    for (int i = 0; i < 4; ++i) {
      const int m0 = mBase + wm + (i << 4) + (quad << 2);
#pragma unroll
      for (int j = 0; j < 4; ++j) {
        const int n = nBase + wn + (j << 4) + col;
        const float e0 = __expf(acc[i][j][0]), e1 = __expf(acc[i][j][1]);
        const float e2 = __expf(acc[i][j][2]), e3 = __expf(acc[i][j][3]);
        csum[i][0] += e0; csum[i][1] += e1; csum[i][2] += e2; csum[i][3] += e3;
        ushort4 s = {bbits(e0), bbits(e1), bbits(e2), bbits(e3)};
        *(ushort4*)(outB + (size_t)b * sOb + (size_t)n * M + m0) = s;
      }
    }
#pragma unroll
    for (int i = 0; i < 4; ++i) {
#pragma unroll
      for (int rg = 0; rg < 4; ++rg) {
        float s = csum[i][rg];
        s += __shfl_xor(s, 1, 64);
        s += __shfl_xor(s, 2, 64);
        s += __shfl_xor(s, 4, 64);
        s += __shfl_xor(s, 8, 64);
        if (col == 0) {
          const int k = mBase + wm + (i << 4) + (quad << 2) + rg;
          atomicAdd(&Z[(size_t)b * M + k], s);
        }
      }
    }
  } else {
#pragma unroll
    for (int i = 0; i < 4; ++i) {
      const int m0 = mBase + wm + (i << 4) + (quad << 2);
#pragma unroll
      for (int j = 0; j < 4; ++j) {
        const int n = nBase + wn + (j << 4) + col;
        const f32x4v v = acc[i][j];
        const size_t base = (size_t)b * sOb + (size_t)n * M + m0;
        if constexpr (MODE == 0) {
          const float4 bb = *(const float4*)(biasSel + m0);
          ushort4 s = {hbits(v[0] + bb.x), hbits(v[1] + bb.y),
                       hbits(v[2] + bb.z), hbits(v[3] + bb.w)};
          *(ushort4*)((unsigned short*)outSel + base) = s;
        } else if constexpr (MODE == 1) {
          const float bv = bias[n];
          ushort4 s = {bbits(v[0] + bv), bbits(v[1] + bv),
                       bbits(v[2] + bv), bbits(v[3] + bv)};
          *(ushort4*)((unsigned short*)outP + base) = s;
        } else {
          const float bv = bias[n];
          const float4 r = *(const float4*)(xres + base);
          float4 o = {v[0] + bv + r.x, v[1] + bv + r.y,
                      v[2] + bv + r.z, v[3] + bv + r.w};
          *(float4*)((float*)outP + base) = o;
        }
      }
    }
  }
}

// ---------------------------------------------------------------------------
// ag GEMM, async register pipeline: NO LDS, NO barriers. D[ic][q].
// A = gs [IC,H] bf16 (rows ic), B = E [q][k] bf16 (rows q), k-contiguous.
// Wave w: ic = w*64..+63; all waves share q-rows (L1-served redundancy).
// Split-K=2 (KC=2048) into P0/P1 fp32, no atomics. Ping-pong prefetch keeps
// ~8 loads/wave in flight; final prefetch overruns 64B into live workspace
// regions (harmless reads).
// ---------------------------------------------------------------------------
__launch_bounds__(256)
__global__ void mgemm_ag(const __hip_bfloat16* __restrict__ Gall,
                         const __hip_bfloat16* __restrict__ Eall,
                         float* __restrict__ P0, float* __restrict__ P1) {
  const int b = blockIdx.z;
  const int kc = blockIdx.x;
  const int qBase = blockIdx.y * 64;
  const int t = threadIdx.x;
  const int lane = t & 63;
  const int w = t >> 6;
  const int r = lane & 15;
  const int koff = (lane >> 4) << 3;
  const int k0 = kc * 2048;

  const unsigned short* __restrict__ gb =
      (const unsigned short*)Gall + (size_t)b * IC * HH;
  const unsigned short* __restrict__ eb =
      (const unsigned short*)Eall + (size_t)b * HH * HH;

  const unsigned short* pa[4];
  const unsigned short* pb[4];
#pragma unroll
  for (int i = 0; i < 4; ++i)
    pa[i] = gb + (size_t)(w * 64 + i * 16 + r) * HH + k0 + koff;
#pragma unroll
  for (int j = 0; j < 4; ++j)
    pb[j] = eb + (size_t)(qBase + j * 16 + r) * HH + k0 + koff;

  f32x4v acc[4][4] = {};
  bf16x8v a0[4], b0[4], a1[4], b1[4];

#pragma unroll
  for (int i = 0; i < 4; ++i) {
    a0[i] = *(const bf16x8v*)pa[i];
    b0[i] = *(const bf16x8v*)pb[i];
  }

  for (int it = 0; it < 64; it += 2) {
#pragma unroll
    for (int i = 0; i < 4; ++i) {
      a1[i] = *(const bf16x8v*)(pa[i] + 32);
      b1[i] = *(const bf16x8v*)(pb[i] + 32);
    }
#pragma unroll
    for (int i = 0; i < 4; ++i)
#pragma unroll
      for (int j = 0; j < 4; ++j)
        acc[i][j] = mfma16(a0[i], b0[j], acc[i][j]);
#pragma unroll
    for (int i = 0; i < 4; ++i) {
      a0[i] = *(const bf16x8v*)(pa[i] + 64);
      b0[i] = *(const bf16x8v*)(pb[i] + 64);
      pa[i] += 64;
      pb[i] += 64;
    }
#pragma unroll
    for (int i = 0; i < 4; ++i)
#pragma unroll
      for (int j = 0; j < 4; ++j)
        acc[i][j] = mfma16(a1[i], b1[j], acc[i][j]);
  }

  float* __restrict__ P = (kc ? P1 : P0) + (size_t)b * HH * IC;
  const int quad = lane >> 4;
  const int col = lane & 15;
#pragma unroll
  for (int i = 0; i < 4; ++i) {
    const int icb = w * 64 + i * 16 + (quad << 2);
#pragma unroll
    for (int j = 0; j < 4; ++j) {
      const int q = qBase + j * 16 + col;
      *(float4*)(P + (size_t)q * IC + icb) = *(float4*)&acc[i][j];
    }
  }
}

// agB = bf16(P0 + P1)
__launch_bounds__(256)
__global__ void cvt_ag(const float* __restrict__ P0, const float* __restrict__ P1,
                       __hip_bfloat16* __restrict__ agB) {
  const size_t tIdx = (size_t)blockIdx.x * 256 + threadIdx.x;
  const float4 u = ((const float4*)P0)[tIdx];
  const float4 v = ((const float4*)P1)[tIdx];
  ushort4 o = {bbits(u.x + v.x), bbits(u.y + v.y), bbits(u.z + v.z), bbits(u.w + v.w)};
  ((ushort4*)agB)[tIdx] = o;
}

// x [B,C,H] fp32 -> xT [B,H,C] fp16
__launch_bounds__(256)
__global__ void xpose(const float* __restrict__ x, __half* __restrict__ xT) {
  __shared__ float tile[64][65];
  const int b = blockIdx.z;
  const int h0 = blockIdx.x * 64;
  const int c0 = blockIdx.y * 64;
  const int lane = threadIdx.x & 63;
  const int r0 = threadIdx.x >> 6;
  const float* xb = x + (size_t)b * CC * HH;
#pragma unroll
  for (int rr = 0; rr < 16; ++rr) {
    const int c = r0 * 16 + rr;
    tile[c][lane] = xb[(size_t)(c0 + c) * HH + h0 + lane];
  }
  __syncthreads();
  __half* ob = xT + (size_t)b * HH * CC;
#pragma unroll
  for (int rr = 0; rr < 16; ++rr) {
    const int hl = r0 * 16 + rr;
    ob[(size_t)(h0 + hl) * CC + c0 + lane] = __float2half(tile[lane][hl]);
  }
}

__global__ void convw(const float* __restrict__ s0, const float* __restrict__ s1,
                      const float* __restrict__ s2, const float* __restrict__ s3,
                      __half* __restrict__ d0, __half* __restrict__ d1,
                      __half* __restrict__ d2, __hip_bfloat16* __restrict__ d3) {
  const int which = blockIdx.y;
  const int i = (blockIdx.x * 256 + threadIdx.x) * 4;
  if (which < 3) {
    const float* s = which == 0 ? s0 : (which == 1 ? s1 : s2);
    __half* d = which == 0 ? d0 : (which == 1 ? d1 : d2);
    const float4 v = *(const float4*)(s + i);
    d[i] = __float2half(v.x); d[i + 1] = __float2half(v.y);
    d[i + 2] = __float2half(v.z); d[i + 3] = __float2half(v.w);
  } else {
    const float4 v = *(const float4*)(s3 + i);
    d3[i] = __float2bfloat16(v.x); d3[i + 1] = __float2bfloat16(v.y);
    d3[i + 2] = __float2bfloat16(v.z); d3[i + 3] = __float2bfloat16(v.w);
  }
}

// gB [B,IC,H] bf16 /= Z[b,h]
__launch_bounds__(256)
__global__ void gscale(unsigned int* __restrict__ g, const float* __restrict__ Z) {
  const size_t tid = (size_t)blockIdx.x * 256 + threadIdx.x;
  const size_t e0 = tid * 8;
  const int b = (int)(e0 >> 20);
  const int h = (int)(e0 & (HH - 1));
  const float* Zp = Z + ((size_t)b << 12) + h;
  uint4 raw = ((const uint4*)g)[tid];
  unsigned short* u = (unsigned short*)&raw;
#pragma unroll
  for (int k = 0; k < 8; ++k) {
    const float f = __uint_as_float(((unsigned)u[k]) << 16) / Zp[k];
    u[k] = bbits(f);
  }
  ((uint4*)g)[tid] = raw;
}

// ---------------------------------------------------------------------------
extern "C" void kernel_launch(void* const* d_in, const int* in_sizes, int n_in,
                              void* d_out, int out_size, void* d_ws, size_t ws_size,
                              hipStream_t stream) {
  (void)in_sizes; (void)n_in; (void)out_size; (void)ws_size;

  const float* x       = (const float*)d_in[0];
  const float* w_phi   = (const float*)d_in[1];
  const float* b_phi   = (const float*)d_in[2];
  const float* w_theta = (const float*)d_in[3];
  const float* b_theta = (const float*)d_in[4];
  const float* w_g     = (const float*)d_in[5];
  const float* b_g     = (const float*)d_in[6];
  const float* w_mask  = (const float*)d_in[7];
  const float* b_mask  = (const float*)d_in[8];
  float* out = (float*)d_out;

  char* p = (char*)d_ws;
  __hip_bfloat16* E = (__hip_bfloat16*)p;           p += (size_t)BB * HH * HH * 2;   // [q][k]
  __half* xT       = (__half*)p;                    p += (size_t)BB * HH * CC * 2;
  __half* thetaH   = (__half*)p;                    p += (size_t)BB * HH * IC * 2;   // [h][ic]
  __half* phiH     = (__half*)p;                    p += (size_t)BB * HH * IC * 2;   // [h][ic]
  __hip_bfloat16* gB  = (__hip_bfloat16*)p;         p += (size_t)BB * IC * HH * 2;   // [ic][h]
  __hip_bfloat16* agB = (__hip_bfloat16*)p;         p += (size_t)BB * HH * IC * 2;   // [h][ic]
  __half* wthH = (__half*)p;                        p += (size_t)IC * CC * 2;
  __half* wphH = (__half*)p;                        p += (size_t)IC * CC * 2;
  __half* wgH  = (__half*)p;                        p += (size_t)IC * CC * 2;
  __hip_bfloat16* wmB = (__hip_bfloat16*)p;         p += (size_t)CC * IC * 2;
  float* Z = (float*)p;                             p += (size_t)BB * HH * 4;
  float* P0 = (float*)thetaH;   // theta+phi dead after scores (16.8 MB)
  float* P1 = (float*)xT;       // xT dead after projections   (16.8 MB)

  const dim3 blk(256);

  convw<<<dim3(128, 4), blk, 0, stream>>>(w_phi, w_theta, w_g, w_mask, wphH, wthH, wgH, wmB);
  xpose<<<dim3(HH / 64, CC / 64, BB), blk, 0, stream>>>(x, xT);

  // theta/phi dual: D[ic][h], A=w_theta/w_phi [IC,C], B=xT [H,C]; out [h][ic] fp16
  mgemm128<0><<<dim3(HH / 128, IC / 128, BB * 2), blk, 0, stream>>>(
      wthH, wphH, xT, thetaH, phiH, b_theta, b_phi, nullptr, nullptr,
      IC, HH, CC, 0, (size_t)HH * CC, (size_t)HH * IC);

  // g: D[h][ic], A=xT [H,C], B=wg [IC,C]; out gB[ic][h] bf16, bias[n=ic]
  mgemm128<1><<<dim3(IC / 128, HH / 128, BB), blk, 0, stream>>>(
      xT, nullptr, wgH, gB, nullptr, b_g, nullptr, nullptr, nullptr,
      HH, IC, CC, (size_t)HH * CC, 0, (size_t)IC * HH);

  // scores: D[k][q], A=phi, B=theta; E[q][k] bf16 + Z[b,k]
  hipMemsetAsync(Z, 0, (size_t)BB * HH * sizeof(float), stream);
  mgemm128<2><<<dim3(HH / 128, HH / 128, BB), blk, 0, stream>>>(
      phiH, nullptr, thetaH, E, nullptr, nullptr, nullptr, nullptr, Z,
      HH, HH, IC, (size_t)HH * IC, (size_t)HH * IC, (size_t)HH * HH);

  gscale<<<dim3((BB * IC * HH / 8) / 256), blk, 0, stream>>>((unsigned int*)gB, Z);

  // ag: async register-pipeline GEMM, split-K=2, no atomics
  mgemm_ag<<<dim3(2, HH / 64, BB), blk, 0, stream>>>(gB, E, P0, P1);
  cvt_ag<<<dim3((BB * HH * IC / 4) / 256), blk, 0, stream>>>(P0, P1, agB);

  // final: D[h][c], A=agB [H,IC], B=wm [C,IC]; out[c][h] fp32 + bias[c] + x
  mgemm128<3><<<dim3(CC / 128, HH / 128, BB), blk, 0, stream>>>(
      agB, nullptr, wmB, out, nullptr, b_mask, nullptr, x, nullptr,
      HH, CC, IC, (size_t)HH * IC, 0, (size_t)CC * HH);
}

// Round 5
// 292.679 us; speedup vs baseline: 1.3426x; 1.3426x over previous
//
#include <hip/hip_runtime.h>
#include <hip/hip_bf16.h>
#include <hip/hip_fp16.h>
#include <type_traits>

constexpr int BB = 4;
constexpr int CC = 512;
constexpr int HH = 4096;
constexpr int IC = 256;

typedef _Float16 f16x8v __attribute__((ext_vector_type(8)));
typedef __bf16   bf16x8v __attribute__((ext_vector_type(8)));
typedef float    f32x4v __attribute__((ext_vector_type(4)));

__device__ __forceinline__ void gll16(const void* g, void* l) {
  __builtin_amdgcn_global_load_lds(
      (const __attribute__((address_space(1))) unsigned int*)g,
      (__attribute__((address_space(3))) unsigned int*)l, 16, 0, 0);
}

__device__ __forceinline__ f32x4v mfma16(f16x8v a, f16x8v b, f32x4v c) {
  return __builtin_amdgcn_mfma_f32_16x16x32_f16(a, b, c, 0, 0, 0);
}
__device__ __forceinline__ f32x4v mfma16(bf16x8v a, bf16x8v b, f32x4v c) {
  return __builtin_amdgcn_mfma_f32_16x16x32_bf16(a, b, c, 0, 0, 0);
}

__device__ __forceinline__ unsigned short hbits(float f) {
  __half h = __float2half(f);
  unsigned short b; __builtin_memcpy(&b, &h, 2); return b;
}
__device__ __forceinline__ unsigned short bbits(float f) {
  __hip_bfloat16 h = __float2bfloat16(f);
  unsigned short b; __builtin_memcpy(&b, &h, 2); return b;
}

// ---------------------------------------------------------------------------
// 128x128-tile B^T GEMM (round-3 proven version): C[m,n] = sum_k A[m,k]*B[n,k].
// 256 thr = 4 waves, each a 64x64 quadrant. C/D: col=lane&15, row=quad*4+reg.
// MODE 0: DUAL theta+phi (blockIdx.z>>2 selects B/bias/out). fp16, +bias[n].
// MODE 1: bf16, +bias[m]                       (g proj -> gB [IC,H])
// MODE 2: bf16 exp(v); Z[b,n] += column sums   (scores -> E [q,k])
// MODE 3: fp32, +bias[m] + xres                (final + residual)
// ---------------------------------------------------------------------------
template <int MODE>
__launch_bounds__(256)
__global__ void mgemm128(const void* __restrict__ Aall, const void* __restrict__ Ball,
                         const void* __restrict__ Ball2,
                         void* __restrict__ outP, void* __restrict__ out2P,
                         const float* __restrict__ bias, const float* __restrict__ bias2,
                         const float* __restrict__ xres, float* __restrict__ Z,
                         int M, int N, int K,
                         size_t sAb, size_t sBb, size_t sOb) {
  using ET = typename std::conditional<MODE == 3, bf16x8v, f16x8v>::type;

  __shared__ __align__(16) unsigned short sA[128 * 32];
  __shared__ __align__(16) unsigned short sB[128 * 32];

  const int zz = blockIdx.z;
  int b, which;
  if constexpr (MODE == 0) { b = zz & (BB - 1); which = zz >> 2; }
  else { b = zz; which = 0; }

  const unsigned short* __restrict__ A = (const unsigned short*)Aall + (size_t)b * sAb;
  const unsigned short* __restrict__ Bm =
      (const unsigned short*)((MODE == 0 && which) ? Ball2 : Ball) + (size_t)b * sBb;
  const float* __restrict__ biasSel = (MODE == 0 && which) ? bias2 : bias;
  void* __restrict__ outSel = (MODE == 0 && which) ? out2P : outP;

  const int t = threadIdx.x;
  const int lane = t & 63;
  const int w = t >> 6;
  const int wm = (w >> 1) << 6;
  const int wn = (w & 1) << 6;
  const int mBase = blockIdx.y * 128;
  const int nBase = blockIdx.x * 128;

  const int fr = lane & 15;
  const int fo = (lane >> 4) << 3;

  f32x4v acc[4][4] = {};

  for (int k0 = 0; k0 < K; k0 += 32) {
#pragma unroll
    for (int p = 0; p < 2; ++p) {
      const int u = t + (p << 8);
      const int r = u >> 2;
      const int cs = (u & 3) << 3;
      gll16(A + (size_t)(mBase + r) * K + (k0 + cs), sA + u * 8);
      gll16(Bm + (size_t)(nBase + r) * K + (k0 + cs), sB + u * 8);
    }
    __syncthreads();
    ET af[4], bf[4];
#pragma unroll
    for (int i = 0; i < 4; ++i)
      af[i] = *(const ET*)(sA + ((wm + (i << 4) + fr) << 5) + fo);
#pragma unroll
    for (int j = 0; j < 4; ++j)
      bf[j] = *(const ET*)(sB + ((wn + (j << 4) + fr) << 5) + fo);
#pragma unroll
    for (int i = 0; i < 4; ++i)
#pragma unroll
      for (int j = 0; j < 4; ++j)
        acc[i][j] = mfma16(af[i], bf[j], acc[i][j]);
    __syncthreads();
  }

  const int row0 = (lane >> 4) << 2;
  const int col = lane & 15;

  if constexpr (MODE == 2) {
    __hip_bfloat16* __restrict__ outB = (__hip_bfloat16*)outP;
    float csum[4] = {0.f, 0.f, 0.f, 0.f};
#pragma unroll
    for (int i = 0; i < 4; ++i) {
      const int m0 = mBase + wm + (i << 4) + row0;
#pragma unroll
      for (int j = 0; j < 4; ++j) {
        const int n = nBase + wn + (j << 4) + col;
        __hip_bfloat16* dst = outB + (size_t)b * sOb + (size_t)m0 * N + n;
#pragma unroll
        for (int rg = 0; rg < 4; ++rg) {
          const float e = __expf(acc[i][j][rg]);
          dst[(size_t)rg * N] = __float2bfloat16(e);
          csum[j] += e;
        }
      }
    }
#pragma unroll
    for (int j = 0; j < 4; ++j) {
      float s = csum[j];
      s += __shfl_xor(s, 16, 64);
      s += __shfl_xor(s, 32, 64);
      if (lane < 16) {
        const int n = nBase + wn + (j << 4) + col;
        atomicAdd(&Z[(size_t)b * N + n], s);
      }
    }
  } else {
#pragma unroll
    for (int i = 0; i < 4; ++i) {
      const int m0 = mBase + wm + (i << 4) + row0;
#pragma unroll
      for (int j = 0; j < 4; ++j) {
        const int n = nBase + wn + (j << 4) + col;
#pragma unroll
        for (int rg = 0; rg < 4; ++rg) {
          const int m = m0 + rg;
          const float v = acc[i][j][rg];
          if constexpr (MODE == 0) {
            ((__half*)outSel)[(size_t)b * sOb + (size_t)m * N + n] =
                __float2half(v + biasSel[n]);
          } else if constexpr (MODE == 1) {
            ((__hip_bfloat16*)outP)[(size_t)b * sOb + (size_t)m * N + n] =
                __float2bfloat16(v + bias[m]);
          } else {
            const size_t o = (size_t)b * sOb + (size_t)m * N + n;
            ((float*)outP)[o] = v + bias[m] + xres[o];
          }
        }
      }
    }
  }
}

// ---------------------------------------------------------------------------
// ag GEMM, split-K=4, NO atomics. D[ic][q] per k-chunk kc.
// m = ic (all 256, wave quadrants), n = q (64-tile). A = gs [IC,H] bf16,
// B = E [q,k] bf16, both k-contiguous. KC=1024, BK=32, 32 iters.
// grid (4, H/64, B) = 1024 blocks -> 4 blocks/CU, 16 waves/CU.
// Partial tile -> fp16 packed ushort4 stores into P16[kc][b][q][ic].
// LDS: sA 256x32 (16KB) + sB 64x32 (4KB) = 20KB -> 4 blocks/CU fits.
// ---------------------------------------------------------------------------
__launch_bounds__(256)
__global__ void mgemm_ag(const __hip_bfloat16* __restrict__ Gall,
                         const __hip_bfloat16* __restrict__ Eall,
                         unsigned short* __restrict__ P16) {
  constexpr int KC = 1024;
  __shared__ __align__(16) unsigned short sA[256 * 32];
  __shared__ __align__(16) unsigned short sB[64 * 32];

  const int b = blockIdx.z;
  const int kc = blockIdx.x;
  const int qBase = blockIdx.y * 64;
  const int k0base = kc * KC;

  const unsigned short* __restrict__ G =
      (const unsigned short*)Gall + (size_t)b * IC * HH;
  const unsigned short* __restrict__ E =
      (const unsigned short*)Eall + (size_t)b * HH * HH;

  const int t = threadIdx.x;
  const int lane = t & 63;
  const int w = t >> 6;
  const int fr = lane & 15;
  const int fo = (lane >> 4) << 3;

  f32x4v acc[4][4] = {};

  for (int kk = 0; kk < KC; kk += 32) {
    const int k0 = k0base + kk;
    // stage A = g tile: 256 rows x 32 k (16 KB) = 4 gll16 per thread
#pragma unroll
    for (int p = 0; p < 4; ++p) {
      const int u = t + (p << 8);
      const int r = u >> 2;
      const int cs = (u & 3) << 3;
      gll16(G + (size_t)r * HH + (k0 + cs), sA + u * 8);
    }
    // stage B = E tile: 64 rows x 32 k (4 KB) = 1 gll16 per thread
    {
      const int r = t >> 2;
      const int cs = (t & 3) << 3;
      gll16(E + (size_t)(qBase + r) * HH + (k0 + cs), sB + t * 8);
    }
    __syncthreads();
    bf16x8v af[4], bf[4];
#pragma unroll
    for (int i = 0; i < 4; ++i)
      af[i] = *(const bf16x8v*)(sA + (((w << 6) + (i << 4) + fr) << 5) + fo);
#pragma unroll
    for (int j = 0; j < 4; ++j)
      bf[j] = *(const bf16x8v*)(sB + (((j << 4) + fr) << 5) + fo);
#pragma unroll
    for (int i = 0; i < 4; ++i)
#pragma unroll
      for (int j = 0; j < 4; ++j)
        acc[i][j] = mfma16(af[i], bf[j], acc[i][j]);
    __syncthreads();
  }

  // D layout: col(n=q)=lane&15, row(m=ic)=quad*4+reg -> reg spans 4 consecutive
  // ic -> packed 8B ushort4 store at P[q*IC + ic0].
  unsigned short* __restrict__ P =
      P16 + ((size_t)kc * BB + b) * HH * IC;
  const int quad = lane >> 4;
  const int col = lane & 15;
#pragma unroll
  for (int i = 0; i < 4; ++i) {
    const int ic0 = (w << 6) + (i << 4) + (quad << 2);
#pragma unroll
    for (int j = 0; j < 4; ++j) {
      const int q = qBase + (j << 4) + col;
      ushort4 s = {hbits(acc[i][j][0]), hbits(acc[i][j][1]),
                   hbits(acc[i][j][2]), hbits(acc[i][j][3])};
      *(ushort4*)(P + (size_t)q * IC + ic0) = s;
    }
  }
}

// agB[b,q,ic] = bf16( sum_kc fp16 P16[kc][b][q][ic] ), 8 elems/thread
__launch_bounds__(256)
__global__ void cvt_ag(const unsigned short* __restrict__ P16,
                       __hip_bfloat16* __restrict__ agB) {
  constexpr size_t CH = (size_t)BB * HH * IC;
  const size_t tIdx = (size_t)blockIdx.x * 256 + threadIdx.x;
  const f16x8v v0 = ((const f16x8v*)(P16))[tIdx];
  const f16x8v v1 = ((const f16x8v*)(P16 + CH))[tIdx];
  const f16x8v v2 = ((const f16x8v*)(P16 + 2 * CH))[tIdx];
  const f16x8v v3 = ((const f16x8v*)(P16 + 3 * CH))[tIdx];
  unsigned short o[8];
#pragma unroll
  for (int k = 0; k < 8; ++k) {
    const float s = (float)v0[k] + (float)v1[k] + (float)v2[k] + (float)v3[k];
    o[k] = bbits(s);
  }
  uint4 pack;
  __builtin_memcpy(&pack, o, 16);
  ((uint4*)agB)[tIdx] = pack;
}

// x [B,C,H] fp32 -> xT [B,H,C] fp16
__launch_bounds__(256)
__global__ void xpose(const float* __restrict__ x, __half* __restrict__ xT) {
  __shared__ float tile[64][65];
  const int b = blockIdx.z;
  const int h0 = blockIdx.x * 64;
  const int c0 = blockIdx.y * 64;
  const int lane = threadIdx.x & 63;
  const int r0 = threadIdx.x >> 6;
  const float* xb = x + (size_t)b * CC * HH;
#pragma unroll
  for (int rr = 0; rr < 16; ++rr) {
    const int c = r0 * 16 + rr;
    tile[c][lane] = xb[(size_t)(c0 + c) * HH + h0 + lane];
  }
  __syncthreads();
  __half* ob = xT + (size_t)b * HH * CC;
#pragma unroll
  for (int rr = 0; rr < 16; ++rr) {
    const int hl = r0 * 16 + rr;
    ob[(size_t)(h0 + hl) * CC + c0 + lane] = __float2half(tile[lane][hl]);
  }
}

__global__ void convw(const float* __restrict__ s0, const float* __restrict__ s1,
                      const float* __restrict__ s2, const float* __restrict__ s3,
                      __half* __restrict__ d0, __half* __restrict__ d1,
                      __half* __restrict__ d2, __hip_bfloat16* __restrict__ d3) {
  const int which = blockIdx.y;
  const int i = (blockIdx.x * 256 + threadIdx.x) * 4;
  if (which < 3) {
    const float* s = which == 0 ? s0 : (which == 1 ? s1 : s2);
    __half* d = which == 0 ? d0 : (which == 1 ? d1 : d2);
    const float4 v = *(const float4*)(s + i);
    d[i] = __float2half(v.x); d[i + 1] = __float2half(v.y);
    d[i + 2] = __float2half(v.z); d[i + 3] = __float2half(v.w);
  } else {
    const float4 v = *(const float4*)(s3 + i);
    d3[i] = __float2bfloat16(v.x); d3[i + 1] = __float2bfloat16(v.y);
    d3[i + 2] = __float2bfloat16(v.z); d3[i + 3] = __float2bfloat16(v.w);
  }
}

// gB [B,IC,H] bf16 /= Z[b,h]
__launch_bounds__(256)
__global__ void gscale(unsigned int* __restrict__ g, const float* __restrict__ Z) {
  const size_t tid = (size_t)blockIdx.x * 256 + threadIdx.x;
  const size_t e0 = tid * 8;
  const int b = (int)(e0 >> 20);
  const int h = (int)(e0 & (HH - 1));
  const float* Zp = Z + ((size_t)b << 12) + h;
  uint4 raw = ((const uint4*)g)[tid];
  unsigned short* u = (unsigned short*)&raw;
#pragma unroll
  for (int k = 0; k < 8; ++k) {
    const float f = __uint_as_float(((unsigned)u[k]) << 16) / Zp[k];
    u[k] = bbits(f);
  }
  ((uint4*)g)[tid] = raw;
}

// ---------------------------------------------------------------------------
extern "C" void kernel_launch(void* const* d_in, const int* in_sizes, int n_in,
                              void* d_out, int out_size, void* d_ws, size_t ws_size,
                              hipStream_t stream) {
  (void)in_sizes; (void)n_in; (void)out_size; (void)ws_size;

  const float* x       = (const float*)d_in[0];
  const float* w_phi   = (const float*)d_in[1];
  const float* b_phi   = (const float*)d_in[2];
  const float* w_theta = (const float*)d_in[3];
  const float* b_theta = (const float*)d_in[4];
  const float* w_g     = (const float*)d_in[5];
  const float* b_g     = (const float*)d_in[6];
  const float* w_mask  = (const float*)d_in[7];
  const float* b_mask  = (const float*)d_in[8];
  float* out = (float*)d_out;

  char* p = (char*)d_ws;
  __hip_bfloat16* E = (__hip_bfloat16*)p;           p += (size_t)BB * HH * HH * 2;   // [q][k]
  __half* xT       = (__half*)p;                    p += (size_t)BB * HH * CC * 2;   // 16.8 MB
  __half* thetaH   = (__half*)p;                    p += (size_t)BB * HH * IC * 2;   // [h][ic]
  __half* phiH     = (__half*)p;                    p += (size_t)BB * HH * IC * 2;   // [h][ic]
  __hip_bfloat16* gB  = (__hip_bfloat16*)p;         p += (size_t)BB * IC * HH * 2;   // [ic][h]
  __hip_bfloat16* agB = (__hip_bfloat16*)p;         p += (size_t)BB * HH * IC * 2;   // [h][ic]
  __half* wthH = (__half*)p;                        p += (size_t)IC * CC * 2;
  __half* wphH = (__half*)p;                        p += (size_t)IC * CC * 2;
  __half* wgH  = (__half*)p;                        p += (size_t)IC * CC * 2;
  __hip_bfloat16* wmB = (__hip_bfloat16*)p;         p += (size_t)CC * IC * 2;
  float* Z = (float*)p;                             p += (size_t)BB * HH * 4;
  // fp16 split-K partials (4 x 8.4 MB = 33.6 MB) alias xT+theta+phi, all dead
  // by the time mgemm_ag runs.
  unsigned short* P16 = (unsigned short*)xT;

  const dim3 blk(256);

  convw<<<dim3(128, 4), blk, 0, stream>>>(w_phi, w_theta, w_g, w_mask, wphH, wthH, wgH, wmB);
  xpose<<<dim3(HH / 64, CC / 64, BB), blk, 0, stream>>>(x, xT);

  // theta/phi dual: A=xT [H,C], B=w_theta/w_phi [IC,C]; out [h][ic] fp16, +bias[ic]
  mgemm128<0><<<dim3(IC / 128, HH / 128, BB * 2), blk, 0, stream>>>(
      xT, wthH, wphH, thetaH, phiH, b_theta, b_phi, nullptr, nullptr,
      HH, IC, CC, (size_t)HH * CC, 0, (size_t)HH * IC);

  // g: A=wg [IC,C], B=xT [H,C]; out gB[ic][h] bf16, +bias[ic=m]
  mgemm128<1><<<dim3(HH / 128, IC / 128, BB), blk, 0, stream>>>(
      wgH, xT, nullptr, gB, nullptr, b_g, nullptr, nullptr, nullptr,
      IC, HH, CC, 0, (size_t)HH * CC, (size_t)IC * HH);

  // scores: A=theta (m=q), B=phi (n=k); E[q][k] bf16 + Z[b,k]
  hipMemsetAsync(Z, 0, (size_t)BB * HH * sizeof(float), stream);
  mgemm128<2><<<dim3(HH / 128, HH / 128, BB), blk, 0, stream>>>(
      thetaH, phiH, nullptr, E, nullptr, nullptr, nullptr, nullptr, Z,
      HH, HH, IC, (size_t)HH * IC, (size_t)HH * IC, (size_t)HH * HH);

  gscale<<<dim3((BB * IC * HH / 8) / 256), blk, 0, stream>>>((unsigned int*)gB, Z);

  // ag: split-K=4, fp16 partials, no atomics
  mgemm_ag<<<dim3(4, HH / 64, BB), blk, 0, stream>>>(gB, E, P16);
  cvt_ag<<<dim3((BB * HH * IC / 8) / 256), blk, 0, stream>>>(P16, agB);

  // final: A=wm [C,IC], B=agB [H,IC]; out[c][h] fp32 + bias[c] + x
  mgemm128<3><<<dim3(HH / 128, CC / 128, BB), blk, 0, stream>>>(
      wmB, agB, nullptr, out, nullptr, b_mask, nullptr, x, nullptr,
      CC, HH, IC, 0, (size_t)HH * IC, (size_t)CC * HH);
}